// Round 20
// baseline (998.312 us; speedup 1.0000x reference)
//
#include <hip/hip_runtime.h>
#include <hip/hip_bf16.h>
#include <cstdint>

// LSTM cell: B=8192, D=1024, U=1024.
// z = [X|H](8192x2048) @ Wcat(2048x4096), gate interleave 16 in N, fused epilogue.
// GEMM: R18 structure (256x256, BK=32, 8 waves 2Mx4N, no setprio) with LDS cut
// to 2 buffers (64KB) + stage-ahead-1 + vmcnt(0)/window so TWO blocks fit per CU
// (16 waves/CU): cross-block TLP fills each block's drain/barrier bubbles at
// unchanged tile shape and HBM traffic (clean test of m114 overlap; R12 was
// confounded by 1.7x HBM). __launch_bounds__(512,4) pins VGPR <= 128 (R18: =128).

using f32x4  = __attribute__((ext_vector_type(4))) float;
using short8 = __attribute__((ext_vector_type(8))) short;

__device__ __forceinline__ unsigned short f2bf(float f) {
  union { float f; unsigned int u; } v; v.f = f;
  unsigned int r = v.u + 0x7fffu + ((v.u >> 16) & 1u);  // RNE
  return (unsigned short)(r >> 16);
}
__device__ __forceinline__ float sigmoidf_fast(float x) { return 1.f / (1.f + __expf(-x)); }
__device__ __forceinline__ float tanhf_fast(float x)    { return 1.f - 2.f / (__expf(2.f * x) + 1.f); }

// ---------- A conversion: Abf[b][k] = bf16(k<1024 ? X[b][k] : H[b][k-1024])
__global__ void conv_a_kernel(const float* __restrict__ X, const float* __restrict__ H,
                              unsigned short* __restrict__ Abf) {
  int idx = blockIdx.x * blockDim.x + threadIdx.x;
  int b  = idx >> 8;
  int kq = (idx & 255) << 2;
  float4 x = *(const float4*)(X + (long)b * 1024 + kq);
  float4 h = *(const float4*)(H + (long)b * 1024 + kq);
  ushort4 xo, ho;
  xo.x = f2bf(x.x); xo.y = f2bf(x.y); xo.z = f2bf(x.z); xo.w = f2bf(x.w);
  ho.x = f2bf(h.x); ho.y = f2bf(h.y); ho.z = f2bf(h.z); ho.w = f2bf(h.w);
  *(ushort4*)(Abf + (long)b * 2048 + kq)        = xo;
  *(ushort4*)(Abf + (long)b * 2048 + 1024 + kq) = ho;
}

// ---------- B conversion: Bt[n][k] bf16, N-major, n = (u>>4)*64 + g*16 + (u&15)
__global__ void conv_b_kernel(const float* W_i, const float* U_i,
                              const float* W_f, const float* U_f,
                              const float* W_c, const float* U_c,
                              const float* W_o, const float* U_o,
                              unsigned short* __restrict__ Bt) {
  __shared__ float tile[64][65];
  int z = blockIdx.z;
  const float* src;
  switch (z) {
    case 0: src = W_i; break; case 1: src = U_i; break;
    case 2: src = W_f; break; case 3: src = U_f; break;
    case 4: src = W_c; break; case 5: src = U_c; break;
    case 6: src = W_o; break; default: src = U_o; break;
  }
  int g = z >> 1, s = z & 1;
  int k0 = blockIdx.x * 64;
  int u0 = blockIdx.y * 64;
  int t = threadIdx.x;
  int c = t & 63, r0 = t >> 6;
#pragma unroll
  for (int i = 0; i < 16; ++i) {
    int r = i * 4 + r0;
    tile[r][c] = src[(long)(k0 + r) * 1024 + u0 + c];
  }
  __syncthreads();
  int ul = t >> 2;
  int ks = (t & 3) * 16;
  unsigned short outv[16];
#pragma unroll
  for (int j = 0; j < 16; ++j) outv[j] = f2bf(tile[ks + j][ul]);
  long n   = 4L * u0 + (ul >> 4) * 64 + g * 16 + (ul & 15);
  long col = (long)s * 1024 + k0 + ks;
  uint4* dst = (uint4*)(Bt + n * 2048 + col);
  dst[0] = *(uint4*)(outv);
  dst[1] = *(uint4*)(outv + 8);
}

// ---------- fused GEMM + LSTM epilogue
// LDS buf (16384 shorts = 32KB): A[256][32] at +0, B[256][32] at +8192. 2 bufs.
__global__ __launch_bounds__(512, 4) void lstm_gemm_kernel(
    const unsigned short* __restrict__ Abf,   // [8192][2048] bf16
    const unsigned short* __restrict__ Btbf,  // [4096][2048] bf16 (N-major)
    const float* __restrict__ b_i, const float* __restrict__ b_f,
    const float* __restrict__ b_c, const float* __restrict__ b_o,
    const float* __restrict__ c_tm1,
    float* __restrict__ outH, float* __restrict__ outC) {
  __shared__ unsigned short smem[32768];  // 64KB -> 2 blocks/CU

  int bid = blockIdx.x;
  int swz = (bid & 7) * 64 + (bid >> 3);  // XCD swizzle, 512 % 8 == 0
  int bm = swz >> 4;   // 32 m-blocks
  int bn = swz & 15;   // 16 n-blocks

  int t = threadIdx.x;
  int lane = t & 63;
  int w = t >> 6;           // 8 waves
  int wm = w >> 2;          // 0..1
  int wn = w & 3;           // 0..3
  int rl = lane & 15;
  int kg = lane >> 4;       // 0..3, 8-elem k-chunk

  // ---- ds_read frag offsets within a buf (XOR chunk swizzle: c ^= (row>>1)&3) ----
#define AOFFE(MI) ((wm * 128 + (MI) * 16 + rl) * 32 + \
    ((kg ^ (((wm * 128 + (MI) * 16 + rl) >> 1) & 3)) << 3))
#define BOFFE(NI) (8192 + (wn * 64 + (NI) * 16 + rl) * 32 + \
    ((kg ^ (((wn * 64 + (NI) * 16 + rl) >> 1) & 3)) << 3))
  const int offA0 = AOFFE(0), offA1 = AOFFE(1), offA2 = AOFFE(2), offA3 = AOFFE(3);
  const int offA4 = AOFFE(4), offA5 = AOFFE(5), offA6 = AOFFE(6), offA7 = AOFFE(7);
  const int offB0 = BOFFE(0), offB1 = BOFFE(1), offB2 = BOFFE(2), offB3 = BOFFE(3);
#undef AOFFE
#undef BOFFE

  // ---- staging: linear LDS dest, inverse-swizzled global source ----
  int srow = t >> 2;                                  // 0..127 (+128 second GLL)
  int cbe  = (((t & 3) ^ ((srow >> 1) & 3))) << 3;    // source k-elem offset
  const unsigned short* aS0 = Abf  + (long)(bm * 256 + srow) * 2048 + cbe;
  const unsigned short* aS1 = aS0 + 128L * 2048;
  const unsigned short* bS0 = Btbf + (long)(bn * 256 + srow) * 2048 + cbe;
  const unsigned short* bS1 = bS0 + 128L * 2048;
  const int dA = t * 8;

#define GLL(SRC, DELM)                                                                     \
  __builtin_amdgcn_global_load_lds((const __attribute__((address_space(1))) void*)(SRC),   \
      (__attribute__((address_space(3))) void*)(&smem[DELM]), 16, 0, 0)
#define VMC(N) asm volatile("s_waitcnt vmcnt(" #N ")" ::: "memory")

  f32x4 acc[8][4];
#pragma unroll
  for (int mi = 0; mi < 8; ++mi)
#pragma unroll
    for (int ni = 0; ni < 4; ++ni) acc[mi][ni] = (f32x4){0.f, 0.f, 0.f, 0.f};

  short8 aw0, aw1, aw2, aw3, bb0, bb1, bb2, bb3;

#define MF4(AF, MI)                                                                      \
  acc[MI][0] = __builtin_amdgcn_mfma_f32_16x16x32_bf16(AF, bb0, acc[MI][0], 0, 0, 0);    \
  acc[MI][1] = __builtin_amdgcn_mfma_f32_16x16x32_bf16(AF, bb1, acc[MI][1], 0, 0, 0);    \
  acc[MI][2] = __builtin_amdgcn_mfma_f32_16x16x32_bf16(AF, bb2, acc[MI][2], 0, 0, 0);    \
  acc[MI][3] = __builtin_amdgcn_mfma_f32_16x16x32_bf16(AF, bb3, acc[MI][3], 0, 0, 0);

// Window w: read buf RB (tile w); stage tile w+1 -> buf RB^1 at source KOFF;
// 32 MFMA; vmcnt(0) drain; barrier. No setprio.
#define WINDOW(RB, KOFF, DOSTAGE, DOSYNC)                                      \
  {                                                                            \
    const unsigned short* Ab_ = smem + (RB) * 16384;                           \
    bb0 = *(const short8*)(Ab_ + offB0);                                       \
    bb1 = *(const short8*)(Ab_ + offB1);                                       \
    bb2 = *(const short8*)(Ab_ + offB2);                                       \
    bb3 = *(const short8*)(Ab_ + offB3);                                       \
    aw0 = *(const short8*)(Ab_ + offA0);                                       \
    aw1 = *(const short8*)(Ab_ + offA1);                                       \
    aw2 = *(const short8*)(Ab_ + offA2);                                       \
    aw3 = *(const short8*)(Ab_ + offA3);                                       \
    if (DOSTAGE) {                                                             \
      GLL(aS0 + (KOFF), ((RB) ^ 1) * 16384 + dA);                              \
      GLL(aS1 + (KOFF), ((RB) ^ 1) * 16384 + 4096 + dA);                       \
    }                                                                          \
    MF4(aw0, 0) MF4(aw1, 1) MF4(aw2, 2) MF4(aw3, 3)                            \
    aw0 = *(const short8*)(Ab_ + offA4);                                       \
    aw1 = *(const short8*)(Ab_ + offA5);                                       \
    aw2 = *(const short8*)(Ab_ + offA6);                                       \
    aw3 = *(const short8*)(Ab_ + offA7);                                       \
    if (DOSTAGE) {                                                             \
      GLL(bS0 + (KOFF), ((RB) ^ 1) * 16384 + 8192 + dA);                       \
      GLL(bS1 + (KOFF), ((RB) ^ 1) * 16384 + 12288 + dA);                      \
    }                                                                          \
    MF4(aw0, 4) MF4(aw1, 5) MF4(aw2, 6) MF4(aw3, 7)                            \
    if (DOSYNC) {                                                              \
      VMC(0);                                                                  \
      __builtin_amdgcn_s_barrier();                                            \
    }                                                                          \
  }

  // ---- prologue: stage tile 0 -> buf0; drain; barrier ----
  GLL(aS0, dA);        GLL(aS1, 4096 + dA);
  GLL(bS0, 8192 + dA); GLL(bS1, 12288 + dA);
  VMC(0);
  __builtin_amdgcn_s_barrier();
  aS0 += 32; aS1 += 32; bS0 += 32; bS1 += 32;   // source base -> tile 1

  // ---- windows 0..61 (31 pairs): window w reads buf w&1, stages tile w+1 ----
  for (int g = 0; g < 31; ++g) {
    WINDOW(0, 0,  1, 1);
    WINDOW(1, 32, 1, 1);
    aS0 += 64; aS1 += 64; bS0 += 64; bS1 += 64;
  }
  // ---- tail: w62 stages tile 63; w63 pure compute ----
  WINDOW(0, 0, 1, 1);
  WINDOW(1, 0, 0, 0);
#undef WINDOW
#undef MF4
#undef VMC
#undef GLL

  // ---- fused LSTM epilogue ----
  // Wave N-span = 64 cols = one u-block: u = nbase/4 + rl; gate = ni.
  int mbase = bm * 256 + wm * 128;
  int nbase = bn * 256 + wn * 64;
  int u = (nbase >> 2) + rl;
  float bi_v = b_i[u], bf_v = b_f[u], bc_v = b_c[u], bo_v = b_o[u];
  int rquad = (lane >> 4) << 2;
#pragma unroll
  for (int mi = 0; mi < 8; ++mi) {
#pragma unroll
    for (int j = 0; j < 4; ++j) {
      int brow = mbase + mi * 16 + rquad + j;
      float zi = acc[mi][0][j] + bi_v;
      float zf = acc[mi][1][j] + bf_v;
      float zc = acc[mi][2][j] + bc_v;
      float zo = acc[mi][3][j] + bo_v;
      float ig = sigmoidf_fast(zi);
      float fg = sigmoidf_fast(zf);
      float cg = tanhf_fast(zc);
      float og = sigmoidf_fast(zo);
      float cp = c_tm1[(long)brow * 1024 + u];
      float cn = fg * cp + ig * cg;
      float hn = og * tanhf_fast(cn);
      outH[(long)brow * 1024 + u] = hn;
      outC[(long)brow * 1024 + u] = cn;
    }
  }
}

extern "C" void kernel_launch(void* const* d_in, const int* in_sizes, int n_in,
                              void* d_out, int out_size, void* d_ws, size_t ws_size,
                              hipStream_t stream) {
  (void)in_sizes; (void)n_in; (void)out_size; (void)ws_size;
  const float* X   = (const float*)d_in[0];
  const float* Hst = (const float*)d_in[1];
  const float* Cst = (const float*)d_in[2];
  const float* W_i = (const float*)d_in[3];
  const float* U_i = (const float*)d_in[4];
  const float* b_i = (const float*)d_in[5];
  const float* W_f = (const float*)d_in[6];
  const float* U_f = (const float*)d_in[7];
  const float* b_f = (const float*)d_in[8];
  const float* W_c = (const float*)d_in[9];
  const float* U_c = (const float*)d_in[10];
  const float* b_c = (const float*)d_in[11];
  const float* W_o = (const float*)d_in[12];
  const float* U_o = (const float*)d_in[13];
  const float* b_o = (const float*)d_in[14];

  unsigned short* Abf  = (unsigned short*)d_ws;                        // 32 MB
  unsigned short* Btbf = (unsigned short*)((char*)d_ws + 33554432);    // 16 MB

  float* outH = (float*)d_out;
  float* outC = outH + 8192L * 1024;

  conv_a_kernel<<<8192, 256, 0, stream>>>(X, Hst, Abf);
  conv_b_kernel<<<dim3(16, 16, 8), 256, 0, stream>>>(W_i, U_i, W_f, U_f, W_c, U_c, W_o, U_o, Btbf);
  lstm_gemm_kernel<<<512, 512, 0, stream>>>(Abf, Btbf, b_i, b_f, b_c, b_o, Cst, outH, outC);
}

// Round 21
// 177.468 us; speedup vs baseline: 5.6253x; 5.6253x over previous
//
#include <hip/hip_runtime.h>
#include <hip/hip_bf16.h>
#include <cstdint>

// LSTM cell: B=8192, D=1024, U=1024.
// z = [X|H](8192x2048) @ Wcat(2048x4096), gate interleave 16 in N, fused epilogue.
// GEMM: R18 structure (256x256, BK=32, 8 waves 2Mx4N, no setprio), LDS cut to
// 2 buffers (64KB) + stage-ahead-1 + vmcnt(0)/window so TWO blocks fit per CU
// (16 waves/CU): cross-block TLP fills drain/barrier bubbles at unchanged tile
// shape and HBM traffic. R20's launch_bounds(512,4) wrongly capped VGPR at 64
// (acc spilled, 2.9GB scratch writes); (512,2) keeps VGPR=128 (4 waves/SIMD
// legal per m69) while LDS=64KB enforces the 2-block co-residency.

using f32x4  = __attribute__((ext_vector_type(4))) float;
using short8 = __attribute__((ext_vector_type(8))) short;

__device__ __forceinline__ unsigned short f2bf(float f) {
  union { float f; unsigned int u; } v; v.f = f;
  unsigned int r = v.u + 0x7fffu + ((v.u >> 16) & 1u);  // RNE
  return (unsigned short)(r >> 16);
}
__device__ __forceinline__ float sigmoidf_fast(float x) { return 1.f / (1.f + __expf(-x)); }
__device__ __forceinline__ float tanhf_fast(float x)    { return 1.f - 2.f / (__expf(2.f * x) + 1.f); }

// ---------- A conversion: Abf[b][k] = bf16(k<1024 ? X[b][k] : H[b][k-1024])
__global__ void conv_a_kernel(const float* __restrict__ X, const float* __restrict__ H,
                              unsigned short* __restrict__ Abf) {
  int idx = blockIdx.x * blockDim.x + threadIdx.x;
  int b  = idx >> 8;
  int kq = (idx & 255) << 2;
  float4 x = *(const float4*)(X + (long)b * 1024 + kq);
  float4 h = *(const float4*)(H + (long)b * 1024 + kq);
  ushort4 xo, ho;
  xo.x = f2bf(x.x); xo.y = f2bf(x.y); xo.z = f2bf(x.z); xo.w = f2bf(x.w);
  ho.x = f2bf(h.x); ho.y = f2bf(h.y); ho.z = f2bf(h.z); ho.w = f2bf(h.w);
  *(ushort4*)(Abf + (long)b * 2048 + kq)        = xo;
  *(ushort4*)(Abf + (long)b * 2048 + 1024 + kq) = ho;
}

// ---------- B conversion: Bt[n][k] bf16, N-major, n = (u>>4)*64 + g*16 + (u&15)
__global__ void conv_b_kernel(const float* W_i, const float* U_i,
                              const float* W_f, const float* U_f,
                              const float* W_c, const float* U_c,
                              const float* W_o, const float* U_o,
                              unsigned short* __restrict__ Bt) {
  __shared__ float tile[64][65];
  int z = blockIdx.z;
  const float* src;
  switch (z) {
    case 0: src = W_i; break; case 1: src = U_i; break;
    case 2: src = W_f; break; case 3: src = U_f; break;
    case 4: src = W_c; break; case 5: src = U_c; break;
    case 6: src = W_o; break; default: src = U_o; break;
  }
  int g = z >> 1, s = z & 1;
  int k0 = blockIdx.x * 64;
  int u0 = blockIdx.y * 64;
  int t = threadIdx.x;
  int c = t & 63, r0 = t >> 6;
#pragma unroll
  for (int i = 0; i < 16; ++i) {
    int r = i * 4 + r0;
    tile[r][c] = src[(long)(k0 + r) * 1024 + u0 + c];
  }
  __syncthreads();
  int ul = t >> 2;
  int ks = (t & 3) * 16;
  unsigned short outv[16];
#pragma unroll
  for (int j = 0; j < 16; ++j) outv[j] = f2bf(tile[ks + j][ul]);
  long n   = 4L * u0 + (ul >> 4) * 64 + g * 16 + (ul & 15);
  long col = (long)s * 1024 + k0 + ks;
  uint4* dst = (uint4*)(Bt + n * 2048 + col);
  dst[0] = *(uint4*)(outv);
  dst[1] = *(uint4*)(outv + 8);
}

// ---------- fused GEMM + LSTM epilogue
// LDS buf (16384 shorts = 32KB): A[256][32] at +0, B[256][32] at +8192. 2 bufs.
__global__ __launch_bounds__(512, 2) void lstm_gemm_kernel(
    const unsigned short* __restrict__ Abf,   // [8192][2048] bf16
    const unsigned short* __restrict__ Btbf,  // [4096][2048] bf16 (N-major)
    const float* __restrict__ b_i, const float* __restrict__ b_f,
    const float* __restrict__ b_c, const float* __restrict__ b_o,
    const float* __restrict__ c_tm1,
    float* __restrict__ outH, float* __restrict__ outC) {
  __shared__ unsigned short smem[32768];  // 64KB -> 2 blocks/CU

  int bid = blockIdx.x;
  int swz = (bid & 7) * 64 + (bid >> 3);  // XCD swizzle, 512 % 8 == 0
  int bm = swz >> 4;   // 32 m-blocks
  int bn = swz & 15;   // 16 n-blocks

  int t = threadIdx.x;
  int lane = t & 63;
  int w = t >> 6;           // 8 waves
  int wm = w >> 2;          // 0..1
  int wn = w & 3;           // 0..3
  int rl = lane & 15;
  int kg = lane >> 4;       // 0..3, 8-elem k-chunk

  // ---- ds_read frag offsets within a buf (XOR chunk swizzle: c ^= (row>>1)&3) ----
#define AOFFE(MI) ((wm * 128 + (MI) * 16 + rl) * 32 + \
    ((kg ^ (((wm * 128 + (MI) * 16 + rl) >> 1) & 3)) << 3))
#define BOFFE(NI) (8192 + (wn * 64 + (NI) * 16 + rl) * 32 + \
    ((kg ^ (((wn * 64 + (NI) * 16 + rl) >> 1) & 3)) << 3))
  const int offA0 = AOFFE(0), offA1 = AOFFE(1), offA2 = AOFFE(2), offA3 = AOFFE(3);
  const int offA4 = AOFFE(4), offA5 = AOFFE(5), offA6 = AOFFE(6), offA7 = AOFFE(7);
  const int offB0 = BOFFE(0), offB1 = BOFFE(1), offB2 = BOFFE(2), offB3 = BOFFE(3);
#undef AOFFE
#undef BOFFE

  // ---- staging: linear LDS dest, inverse-swizzled global source ----
  int srow = t >> 2;                                  // 0..127 (+128 second GLL)
  int cbe  = (((t & 3) ^ ((srow >> 1) & 3))) << 3;    // source k-elem offset
  const unsigned short* aS0 = Abf  + (long)(bm * 256 + srow) * 2048 + cbe;
  const unsigned short* aS1 = aS0 + 128L * 2048;
  const unsigned short* bS0 = Btbf + (long)(bn * 256 + srow) * 2048 + cbe;
  const unsigned short* bS1 = bS0 + 128L * 2048;
  const int dA = t * 8;

#define GLL(SRC, DELM)                                                                     \
  __builtin_amdgcn_global_load_lds((const __attribute__((address_space(1))) void*)(SRC),   \
      (__attribute__((address_space(3))) void*)(&smem[DELM]), 16, 0, 0)
#define VMC(N) asm volatile("s_waitcnt vmcnt(" #N ")" ::: "memory")

  f32x4 acc[8][4];
#pragma unroll
  for (int mi = 0; mi < 8; ++mi)
#pragma unroll
    for (int ni = 0; ni < 4; ++ni) acc[mi][ni] = (f32x4){0.f, 0.f, 0.f, 0.f};

  short8 aw0, aw1, aw2, aw3, bb0, bb1, bb2, bb3;

#define MF4(AF, MI)                                                                      \
  acc[MI][0] = __builtin_amdgcn_mfma_f32_16x16x32_bf16(AF, bb0, acc[MI][0], 0, 0, 0);    \
  acc[MI][1] = __builtin_amdgcn_mfma_f32_16x16x32_bf16(AF, bb1, acc[MI][1], 0, 0, 0);    \
  acc[MI][2] = __builtin_amdgcn_mfma_f32_16x16x32_bf16(AF, bb2, acc[MI][2], 0, 0, 0);    \
  acc[MI][3] = __builtin_amdgcn_mfma_f32_16x16x32_bf16(AF, bb3, acc[MI][3], 0, 0, 0);

// Window w: read buf RB (tile w); stage tile w+1 -> buf RB^1 at source KOFF;
// 32 MFMA; vmcnt(0) drain; barrier. No setprio.
#define WINDOW(RB, KOFF, DOSTAGE, DOSYNC)                                      \
  {                                                                            \
    const unsigned short* Ab_ = smem + (RB) * 16384;                           \
    bb0 = *(const short8*)(Ab_ + offB0);                                       \
    bb1 = *(const short8*)(Ab_ + offB1);                                       \
    bb2 = *(const short8*)(Ab_ + offB2);                                       \
    bb3 = *(const short8*)(Ab_ + offB3);                                       \
    aw0 = *(const short8*)(Ab_ + offA0);                                       \
    aw1 = *(const short8*)(Ab_ + offA1);                                       \
    aw2 = *(const short8*)(Ab_ + offA2);                                       \
    aw3 = *(const short8*)(Ab_ + offA3);                                       \
    if (DOSTAGE) {                                                             \
      GLL(aS0 + (KOFF), ((RB) ^ 1) * 16384 + dA);                              \
      GLL(aS1 + (KOFF), ((RB) ^ 1) * 16384 + 4096 + dA);                       \
    }                                                                          \
    MF4(aw0, 0) MF4(aw1, 1) MF4(aw2, 2) MF4(aw3, 3)                            \
    aw0 = *(const short8*)(Ab_ + offA4);                                       \
    aw1 = *(const short8*)(Ab_ + offA5);                                       \
    aw2 = *(const short8*)(Ab_ + offA6);                                       \
    aw3 = *(const short8*)(Ab_ + offA7);                                       \
    if (DOSTAGE) {                                                             \
      GLL(bS0 + (KOFF), ((RB) ^ 1) * 16384 + 8192 + dA);                       \
      GLL(bS1 + (KOFF), ((RB) ^ 1) * 16384 + 12288 + dA);                      \
    }                                                                          \
    MF4(aw0, 4) MF4(aw1, 5) MF4(aw2, 6) MF4(aw3, 7)                            \
    if (DOSYNC) {                                                              \
      VMC(0);                                                                  \
      __builtin_amdgcn_s_barrier();                                            \
    }                                                                          \
  }

  // ---- prologue: stage tile 0 -> buf0; drain; barrier ----
  GLL(aS0, dA);        GLL(aS1, 4096 + dA);
  GLL(bS0, 8192 + dA); GLL(bS1, 12288 + dA);
  VMC(0);
  __builtin_amdgcn_s_barrier();
  aS0 += 32; aS1 += 32; bS0 += 32; bS1 += 32;   // source base -> tile 1

  // ---- windows 0..61 (31 pairs): window w reads buf w&1, stages tile w+1 ----
  for (int g = 0; g < 31; ++g) {
    WINDOW(0, 0,  1, 1);
    WINDOW(1, 32, 1, 1);
    aS0 += 64; aS1 += 64; bS0 += 64; bS1 += 64;
  }
  // ---- tail: w62 stages tile 63; w63 pure compute ----
  WINDOW(0, 0, 1, 1);
  WINDOW(1, 0, 0, 0);
#undef WINDOW
#undef MF4
#undef VMC
#undef GLL

  // ---- fused LSTM epilogue ----
  // Wave N-span = 64 cols = one u-block: u = nbase/4 + rl; gate = ni.
  int mbase = bm * 256 + wm * 128;
  int nbase = bn * 256 + wn * 64;
  int u = (nbase >> 2) + rl;
  float bi_v = b_i[u], bf_v = b_f[u], bc_v = b_c[u], bo_v = b_o[u];
  int rquad = (lane >> 4) << 2;
#pragma unroll
  for (int mi = 0; mi < 8; ++mi) {
#pragma unroll
    for (int j = 0; j < 4; ++j) {
      int brow = mbase + mi * 16 + rquad + j;
      float zi = acc[mi][0][j] + bi_v;
      float zf = acc[mi][1][j] + bf_v;
      float zc = acc[mi][2][j] + bc_v;
      float zo = acc[mi][3][j] + bo_v;
      float ig = sigmoidf_fast(zi);
      float fg = sigmoidf_fast(zf);
      float cg = tanhf_fast(zc);
      float og = sigmoidf_fast(zo);
      float cp = c_tm1[(long)brow * 1024 + u];
      float cn = fg * cp + ig * cg;
      float hn = og * tanhf_fast(cn);
      outH[(long)brow * 1024 + u] = hn;
      outC[(long)brow * 1024 + u] = cn;
    }
  }
}

extern "C" void kernel_launch(void* const* d_in, const int* in_sizes, int n_in,
                              void* d_out, int out_size, void* d_ws, size_t ws_size,
                              hipStream_t stream) {
  (void)in_sizes; (void)n_in; (void)out_size; (void)ws_size;
  const float* X   = (const float*)d_in[0];
  const float* Hst = (const float*)d_in[1];
  const float* Cst = (const float*)d_in[2];
  const float* W_i = (const float*)d_in[3];
  const float* U_i = (const float*)d_in[4];
  const float* b_i = (const float*)d_in[5];
  const float* W_f = (const float*)d_in[6];
  const float* U_f = (const float*)d_in[7];
  const float* b_f = (const float*)d_in[8];
  const float* W_c = (const float*)d_in[9];
  const float* U_c = (const float*)d_in[10];
  const float* b_c = (const float*)d_in[11];
  const float* W_o = (const float*)d_in[12];
  const float* U_o = (const float*)d_in[13];
  const float* b_o = (const float*)d_in[14];

  unsigned short* Abf  = (unsigned short*)d_ws;                        // 32 MB
  unsigned short* Btbf = (unsigned short*)((char*)d_ws + 33554432);    // 16 MB

  float* outH = (float*)d_out;
  float* outC = outH + 8192L * 1024;

  conv_a_kernel<<<8192, 256, 0, stream>>>(X, Hst, Abf);
  conv_b_kernel<<<dim3(16, 16, 8), 256, 0, stream>>>(W_i, U_i, W_f, U_f, W_c, U_c, W_o, U_o, Btbf);
  lstm_gemm_kernel<<<512, 512, 0, stream>>>(Abf, Btbf, b_i, b_f, b_c, b_o, Cst, outH, outC);
}

// Round 22
// 159.626 us; speedup vs baseline: 6.2541x; 1.1118x over previous
//
#include <hip/hip_runtime.h>
#include <hip/hip_bf16.h>
#include <cstdint>

// LSTM cell: B=8192, D=1024, U=1024.  FINAL (= round-18 best: 153.6us total).
// z = [X|H](8192x2048) @ Wcat(2048x4096), gate interleave 16 in N, fused epilogue.
// GEMM: 256x256 tile, BK=32, 8 waves (2Mx4N), 3 LDS bufs (96KB), one
// vmcnt(4)+barrier per K-window, stage-ahead-2 via global_load_lds(16B),
// XOR-chunk LDS swizzle (0 bank conflicts), no setprio. 961 TF (38.5% dense).

using f32x4  = __attribute__((ext_vector_type(4))) float;
using short8 = __attribute__((ext_vector_type(8))) short;

__device__ __forceinline__ unsigned short f2bf(float f) {
  union { float f; unsigned int u; } v; v.f = f;
  unsigned int r = v.u + 0x7fffu + ((v.u >> 16) & 1u);  // RNE
  return (unsigned short)(r >> 16);
}
__device__ __forceinline__ float sigmoidf_fast(float x) { return 1.f / (1.f + __expf(-x)); }
__device__ __forceinline__ float tanhf_fast(float x)    { return 1.f - 2.f / (__expf(2.f * x) + 1.f); }

// ---------- A conversion: Abf[b][k] = bf16(k<1024 ? X[b][k] : H[b][k-1024])
__global__ void conv_a_kernel(const float* __restrict__ X, const float* __restrict__ H,
                              unsigned short* __restrict__ Abf) {
  int idx = blockIdx.x * blockDim.x + threadIdx.x;
  int b  = idx >> 8;
  int kq = (idx & 255) << 2;
  float4 x = *(const float4*)(X + (long)b * 1024 + kq);
  float4 h = *(const float4*)(H + (long)b * 1024 + kq);
  ushort4 xo, ho;
  xo.x = f2bf(x.x); xo.y = f2bf(x.y); xo.z = f2bf(x.z); xo.w = f2bf(x.w);
  ho.x = f2bf(h.x); ho.y = f2bf(h.y); ho.z = f2bf(h.z); ho.w = f2bf(h.w);
  *(ushort4*)(Abf + (long)b * 2048 + kq)        = xo;
  *(ushort4*)(Abf + (long)b * 2048 + 1024 + kq) = ho;
}

// ---------- B conversion: Bt[n][k] bf16, N-major, n = (u>>4)*64 + g*16 + (u&15)
__global__ void conv_b_kernel(const float* W_i, const float* U_i,
                              const float* W_f, const float* U_f,
                              const float* W_c, const float* U_c,
                              const float* W_o, const float* U_o,
                              unsigned short* __restrict__ Bt) {
  __shared__ float tile[64][65];
  int z = blockIdx.z;
  const float* src;
  switch (z) {
    case 0: src = W_i; break; case 1: src = U_i; break;
    case 2: src = W_f; break; case 3: src = U_f; break;
    case 4: src = W_c; break; case 5: src = U_c; break;
    case 6: src = W_o; break; default: src = U_o; break;
  }
  int g = z >> 1, s = z & 1;
  int k0 = blockIdx.x * 64;
  int u0 = blockIdx.y * 64;
  int t = threadIdx.x;
  int c = t & 63, r0 = t >> 6;
#pragma unroll
  for (int i = 0; i < 16; ++i) {
    int r = i * 4 + r0;
    tile[r][c] = src[(long)(k0 + r) * 1024 + u0 + c];
  }
  __syncthreads();
  int ul = t >> 2;
  int ks = (t & 3) * 16;
  unsigned short outv[16];
#pragma unroll
  for (int j = 0; j < 16; ++j) outv[j] = f2bf(tile[ks + j][ul]);
  long n   = 4L * u0 + (ul >> 4) * 64 + g * 16 + (ul & 15);
  long col = (long)s * 1024 + k0 + ks;
  uint4* dst = (uint4*)(Bt + n * 2048 + col);
  dst[0] = *(uint4*)(outv);
  dst[1] = *(uint4*)(outv + 8);
}

// ---------- fused GEMM + LSTM epilogue
// LDS buf (16384 shorts = 32KB): A[256][32] at +0, B[256][32] at +8192. 3 bufs.
__global__ __launch_bounds__(512, 2) void lstm_gemm_kernel(
    const unsigned short* __restrict__ Abf,   // [8192][2048] bf16
    const unsigned short* __restrict__ Btbf,  // [4096][2048] bf16 (N-major)
    const float* __restrict__ b_i, const float* __restrict__ b_f,
    const float* __restrict__ b_c, const float* __restrict__ b_o,
    const float* __restrict__ c_tm1,
    float* __restrict__ outH, float* __restrict__ outC) {
  __shared__ unsigned short smem[49152];  // 96KB

  int bid = blockIdx.x;
  int swz = (bid & 7) * 64 + (bid >> 3);  // XCD swizzle, 512 % 8 == 0
  int bm = swz >> 4;   // 32 m-blocks
  int bn = swz & 15;   // 16 n-blocks

  int t = threadIdx.x;
  int lane = t & 63;
  int w = t >> 6;           // 8 waves
  int wm = w >> 2;          // 0..1
  int wn = w & 3;           // 0..3
  int rl = lane & 15;
  int kg = lane >> 4;       // 0..3, 8-elem k-chunk

  // ---- ds_read frag offsets within a buf (XOR chunk swizzle: c ^= (row>>1)&3) ----
#define AOFFE(MI) ((wm * 128 + (MI) * 16 + rl) * 32 + \
    ((kg ^ (((wm * 128 + (MI) * 16 + rl) >> 1) & 3)) << 3))
#define BOFFE(NI) (8192 + (wn * 64 + (NI) * 16 + rl) * 32 + \
    ((kg ^ (((wn * 64 + (NI) * 16 + rl) >> 1) & 3)) << 3))
  const int offA0 = AOFFE(0), offA1 = AOFFE(1), offA2 = AOFFE(2), offA3 = AOFFE(3);
  const int offA4 = AOFFE(4), offA5 = AOFFE(5), offA6 = AOFFE(6), offA7 = AOFFE(7);
  const int offB0 = BOFFE(0), offB1 = BOFFE(1), offB2 = BOFFE(2), offB3 = BOFFE(3);
#undef AOFFE
#undef BOFFE

  // ---- staging: linear LDS dest, inverse-swizzled global source ----
  int srow = t >> 2;                                  // 0..127 (+128 second GLL)
  int cbe  = (((t & 3) ^ ((srow >> 1) & 3))) << 3;    // source k-elem offset
  const unsigned short* aS0 = Abf  + (long)(bm * 256 + srow) * 2048 + cbe;
  const unsigned short* aS1 = aS0 + 128L * 2048;
  const unsigned short* bS0 = Btbf + (long)(bn * 256 + srow) * 2048 + cbe;
  const unsigned short* bS1 = bS0 + 128L * 2048;
  const int dA = t * 8;

#define GLL(SRC, DELM)                                                                     \
  __builtin_amdgcn_global_load_lds((const __attribute__((address_space(1))) void*)(SRC),   \
      (__attribute__((address_space(3))) void*)(&smem[DELM]), 16, 0, 0)
#define VMC(N) asm volatile("s_waitcnt vmcnt(" #N ")" ::: "memory")

  f32x4 acc[8][4];
#pragma unroll
  for (int mi = 0; mi < 8; ++mi)
#pragma unroll
    for (int ni = 0; ni < 4; ++ni) acc[mi][ni] = (f32x4){0.f, 0.f, 0.f, 0.f};

  short8 aw0, aw1, aw2, aw3, bb0, bb1, bb2, bb3;

#define MF4(AF, MI)                                                                      \
  acc[MI][0] = __builtin_amdgcn_mfma_f32_16x16x32_bf16(AF, bb0, acc[MI][0], 0, 0, 0);    \
  acc[MI][1] = __builtin_amdgcn_mfma_f32_16x16x32_bf16(AF, bb1, acc[MI][1], 0, 0, 0);    \
  acc[MI][2] = __builtin_amdgcn_mfma_f32_16x16x32_bf16(AF, bb2, acc[MI][2], 0, 0, 0);    \
  acc[MI][3] = __builtin_amdgcn_mfma_f32_16x16x32_bf16(AF, bb3, acc[MI][3], 0, 0, 0);

// One K-tile window: read buf RB, stage tile (into buf SB) at source offset KOFF,
// counted vmcnt + single barrier at end. No setprio.
#define WINDOW(RB, SB, KOFF, DOSTAGE, VMN, DOBAR)                              \
  {                                                                            \
    const unsigned short* Ab_ = smem + (RB) * 16384;                           \
    bb0 = *(const short8*)(Ab_ + offB0);                                       \
    bb1 = *(const short8*)(Ab_ + offB1);                                       \
    bb2 = *(const short8*)(Ab_ + offB2);                                       \
    bb3 = *(const short8*)(Ab_ + offB3);                                       \
    aw0 = *(const short8*)(Ab_ + offA0);                                       \
    aw1 = *(const short8*)(Ab_ + offA1);                                       \
    aw2 = *(const short8*)(Ab_ + offA2);                                       \
    aw3 = *(const short8*)(Ab_ + offA3);                                       \
    if (DOSTAGE) {                                                             \
      GLL(aS0 + (KOFF), (SB) * 16384 + dA);                                    \
      GLL(aS1 + (KOFF), (SB) * 16384 + 4096 + dA);                             \
    }                                                                          \
    MF4(aw0, 0) MF4(aw1, 1) MF4(aw2, 2) MF4(aw3, 3)                            \
    aw0 = *(const short8*)(Ab_ + offA4);                                       \
    aw1 = *(const short8*)(Ab_ + offA5);                                       \
    aw2 = *(const short8*)(Ab_ + offA6);                                       \
    aw3 = *(const short8*)(Ab_ + offA7);                                       \
    if (DOSTAGE) {                                                             \
      GLL(bS0 + (KOFF), (SB) * 16384 + 8192 + dA);                             \
      GLL(bS1 + (KOFF), (SB) * 16384 + 12288 + dA);                            \
    }                                                                          \
    MF4(aw0, 4) MF4(aw1, 5) MF4(aw2, 6) MF4(aw3, 7)                            \
    if ((VMN) == 4) VMC(4);                                                    \
    if ((VMN) == 0) VMC(0);                                                    \
    if (DOBAR) __builtin_amdgcn_s_barrier();                                   \
  }

  // ---- prologue: stage tiles 0 -> buf0, 1 -> buf1; drain tile 0 only ----
  GLL(aS0, dA);            GLL(aS1, 4096 + dA);
  GLL(bS0, 8192 + dA);     GLL(bS1, 12288 + dA);
  GLL(aS0 + 32, 16384 + dA);        GLL(aS1 + 32, 16384 + 4096 + dA);
  GLL(bS0 + 32, 16384 + 8192 + dA); GLL(bS1 + 32, 16384 + 12288 + dA);
  VMC(4);
  __builtin_amdgcn_s_barrier();
  aS0 += 64; aS1 += 64; bS0 += 64; bS1 += 64;   // source base -> tile 2

  // ---- windows 0..59 (stage tiles 2..61) ----
  for (int g = 0; g < 20; ++g) {
    WINDOW(0, 2, 0,  1, 4, 1);
    WINDOW(1, 0, 32, 1, 4, 1);
    WINDOW(2, 1, 64, 1, 4, 1);
    aS0 += 96; aS1 += 96; bS0 += 96; bS1 += 96;
  }
  // ---- tail: w60 stages t62, w61 stages t63, w62 drains, w63 pure compute ----
  WINDOW(0, 2, 0,  1, 4, 1);
  WINDOW(1, 0, 32, 1, 4, 1);
  WINDOW(2, 0, 0,  0, 0, 1);
  WINDOW(0, 0, 0,  0, -1, 0);
#undef WINDOW
#undef MF4
#undef VMC
#undef GLL

  // ---- fused LSTM epilogue ----
  // Wave N-span = 64 cols = one u-block: u = nbase/4 + rl; gate = ni.
  int mbase = bm * 256 + wm * 128;
  int nbase = bn * 256 + wn * 64;
  int u = (nbase >> 2) + rl;
  float bi_v = b_i[u], bf_v = b_f[u], bc_v = b_c[u], bo_v = b_o[u];
  int rquad = (lane >> 4) << 2;
#pragma unroll
  for (int mi = 0; mi < 8; ++mi) {
#pragma unroll
    for (int j = 0; j < 4; ++j) {
      int brow = mbase + mi * 16 + rquad + j;
      float zi = acc[mi][0][j] + bi_v;
      float zf = acc[mi][1][j] + bf_v;
      float zc = acc[mi][2][j] + bc_v;
      float zo = acc[mi][3][j] + bo_v;
      float ig = sigmoidf_fast(zi);
      float fg = sigmoidf_fast(zf);
      float cg = tanhf_fast(zc);
      float og = sigmoidf_fast(zo);
      float cp = c_tm1[(long)brow * 1024 + u];
      float cn = fg * cp + ig * cg;
      float hn = og * tanhf_fast(cn);
      outH[(long)brow * 1024 + u] = hn;
      outC[(long)brow * 1024 + u] = cn;
    }
  }
}

extern "C" void kernel_launch(void* const* d_in, const int* in_sizes, int n_in,
                              void* d_out, int out_size, void* d_ws, size_t ws_size,
                              hipStream_t stream) {
  (void)in_sizes; (void)n_in; (void)out_size; (void)ws_size;
  const float* X   = (const float*)d_in[0];
  const float* Hst = (const float*)d_in[1];
  const float* Cst = (const float*)d_in[2];
  const float* W_i = (const float*)d_in[3];
  const float* U_i = (const float*)d_in[4];
  const float* b_i = (const float*)d_in[5];
  const float* W_f = (const float*)d_in[6];
  const float* U_f = (const float*)d_in[7];
  const float* b_f = (const float*)d_in[8];
  const float* W_c = (const float*)d_in[9];
  const float* U_c = (const float*)d_in[10];
  const float* b_c = (const float*)d_in[11];
  const float* W_o = (const float*)d_in[12];
  const float* U_o = (const float*)d_in[13];
  const float* b_o = (const float*)d_in[14];

  unsigned short* Abf  = (unsigned short*)d_ws;                        // 32 MB
  unsigned short* Btbf = (unsigned short*)((char*)d_ws + 33554432);    // 16 MB

  float* outH = (float*)d_out;
  float* outC = outH + 8192L * 1024;

  conv_a_kernel<<<8192, 256, 0, stream>>>(X, Hst, Abf);
  conv_b_kernel<<<dim3(16, 16, 8), 256, 0, stream>>>(W_i, U_i, W_f, U_f, W_c, U_c, W_o, U_o, Btbf);
  lstm_gemm_kernel<<<512, 512, 0, stream>>>(Abf, Btbf, b_i, b_f, b_c, b_o, Cst, outH, outC);
}